// Round 1
// baseline (766.491 us; speedup 1.0000x reference)
//
#include <hip/hip_runtime.h>

namespace {
constexpr int kH = 4, kD = 32, kEF = 32, kNT = 4, kET = 8;
constexpr int kHD = kH * kD;  // 128
constexpr float kNegSlope = 0.2f;

__device__ __forceinline__ float lrelu(float x) { return x > 0.f ? x : kNegSlope * x; }
__device__ __forceinline__ float get4(const float4& v, int i) {
  return i == 0 ? v.x : i == 1 ? v.y : i == 2 ? v.z : v.w;
}

// ee[t,h] = sum_f ( sum_k edge_emb[t,k] * W_e[(h*EF+f),k] ) * attn_e[h,f]
__global__ void k_prep_ee(const float* __restrict__ edge_emb,
                          const float* __restrict__ W_e,
                          const float* __restrict__ attn_e,
                          float* __restrict__ ee_tab) {
  int t = threadIdx.x;
  if (t < kET * kH) {
    int et = t / kH, h = t % kH;
    float acc = 0.f;
    for (int f = 0; f < kEF; ++f) {
      const float* wrow = W_e + (h * kEF + f) * kEF;
      const float* erow = edge_emb + et * kEF;
      float emb = 0.f;
      for (int k = 0; k < kEF; ++k) emb += erow[k] * wrow[k];
      acc += emb * attn_e[h * kEF + f];
    }
    ee_tab[et * kH + h] = acc;
  }
}

// one wave per node: el[n,h] = sum_d feat*fc[nt]*attn_l ; er likewise
__global__ void k_node(const float* __restrict__ feat, const float* __restrict__ fc,
                       const float* __restrict__ attn_l, const float* __restrict__ attn_r,
                       const int* __restrict__ node_types,
                       float* __restrict__ el, float* __restrict__ er, int N) {
  int gid = blockIdx.x * blockDim.x + threadIdx.x;
  int node = gid >> 6;
  int lane = threadIdx.x & 63;
  if (node >= N) return;
  int nt = node_types[node];
  float2 f2 = *(const float2*)(feat + node * kHD + lane * 2);
  float2 c2 = *(const float2*)(fc + nt * kHD + lane * 2);
  float2 al = *(const float2*)(attn_l + lane * 2);
  float2 ar = *(const float2*)(attn_r + lane * 2);
  float fx = f2.x * c2.x, fy = f2.y * c2.y;
  float pl = fx * al.x + fy * al.y;
  float pr = fx * ar.x + fy * ar.y;
#pragma unroll
  for (int off = 1; off < 16; off <<= 1) {  // reduce within 16-lane head groups
    pl += __shfl_xor(pl, off);
    pr += __shfl_xor(pr, off);
  }
  if ((lane & 15) == 0) {
    int h = lane >> 4;
    el[node * kH + h] = pl;
    er[node * kH + h] = pr;
  }
}

__global__ void k_hist(const int* __restrict__ dst, int* __restrict__ cnt, int E) {
  int i = blockIdx.x * blockDim.x + threadIdx.x;
  if (i < E) atomicAdd(&cnt[dst[i]], 1);
}

constexpr int kScanB = 256;

__global__ void k_scan1(const int* __restrict__ cnt, int* __restrict__ scanbuf,
                        int* __restrict__ bsum, int N) {
  __shared__ int sh[kScanB];
  int i = blockIdx.x * kScanB + threadIdx.x;
  int x = (i < N) ? cnt[i] : 0;
  sh[threadIdx.x] = x;
  __syncthreads();
  for (int off = 1; off < kScanB; off <<= 1) {
    int v = (threadIdx.x >= off) ? sh[threadIdx.x - off] : 0;
    __syncthreads();
    sh[threadIdx.x] += v;
    __syncthreads();
  }
  if (i < N) scanbuf[i] = sh[threadIdx.x];
  if (threadIdx.x == kScanB - 1) bsum[blockIdx.x] = sh[kScanB - 1];
}

__global__ void k_scan2(int* __restrict__ bsum, int nb) {
  __shared__ int sh[1024];
  int t = threadIdx.x;
  int x = (t < nb) ? bsum[t] : 0;
  sh[t] = x;
  __syncthreads();
  for (int off = 1; off < 1024; off <<= 1) {
    int v = (t >= off) ? sh[t - off] : 0;
    __syncthreads();
    sh[t] += v;
    __syncthreads();
  }
  if (t < nb) bsum[t] = sh[t];  // inclusive
}

__global__ void k_scan3(const int* __restrict__ cnt, const int* __restrict__ scanbuf,
                        const int* __restrict__ bsum, int* __restrict__ ptr,
                        int* __restrict__ cur, int N) {
  int i = blockIdx.x * kScanB + threadIdx.x;
  if (i >= N) return;
  int incl = scanbuf[i] + (blockIdx.x ? bsum[blockIdx.x - 1] : 0);
  int excl = incl - cnt[i];
  ptr[i] = excl;
  cur[i] = excl;
  if (i == N - 1) ptr[N] = incl;
}

__global__ void k_scatter(const int* __restrict__ dst, int* __restrict__ cur,
                          int* __restrict__ csr_eid, int E) {
  int i = blockIdx.x * blockDim.x + threadIdx.x;
  if (i < E) {
    int p = atomicAdd(&cur[dst[i]], 1);
    csr_eid[p] = i;
  }
}

// one wave per dst node: segment softmax (max, sum, normalize) + aggregation, no atomics
__global__ void __launch_bounds__(256) k_fused(
    const float* __restrict__ feat, const float* __restrict__ fc,
    const int* __restrict__ node_types, const int* __restrict__ src,
    const int* __restrict__ e_feat, const float* __restrict__ el,
    const float* __restrict__ er, const float* __restrict__ ee_tab,
    const int* __restrict__ ptr, const int* __restrict__ csr_eid,
    float* __restrict__ rst, float* __restrict__ out_a, int N) {
  __shared__ float fc_sh[kNT * kHD];
  __shared__ __align__(16) float ee_sh[kET * kH];
  for (int i = threadIdx.x; i < kNT * kHD; i += blockDim.x) fc_sh[i] = fc[i];
  if (threadIdx.x < kET * kH) ee_sh[threadIdx.x] = ee_tab[threadIdx.x];
  __syncthreads();
  int lane = threadIdx.x & 63;
  int node = blockIdx.x * (blockDim.x >> 6) + (threadIdx.x >> 6);
  if (node >= N) return;
  int start = ptr[node], end = ptr[node + 1];
  float4 erv = *(const float4*)(er + node * kH);

  // pass 1: segment max per head (lane-per-edge)
  float4 mx = make_float4(-3e38f, -3e38f, -3e38f, -3e38f);
  for (int j = start + lane; j < end; j += 64) {
    int eid = csr_eid[j];
    int s = src[eid], et = e_feat[eid];
    float4 elv = *(const float4*)(el + s * kH);
    float4 ee = *(const float4*)(ee_sh + et * kH);
    mx.x = fmaxf(mx.x, lrelu(elv.x + erv.x + ee.x));
    mx.y = fmaxf(mx.y, lrelu(elv.y + erv.y + ee.y));
    mx.z = fmaxf(mx.z, lrelu(elv.z + erv.z + ee.z));
    mx.w = fmaxf(mx.w, lrelu(elv.w + erv.w + ee.w));
  }
#pragma unroll
  for (int off = 1; off < 64; off <<= 1) {
    mx.x = fmaxf(mx.x, __shfl_xor(mx.x, off));
    mx.y = fmaxf(mx.y, __shfl_xor(mx.y, off));
    mx.z = fmaxf(mx.z, __shfl_xor(mx.z, off));
    mx.w = fmaxf(mx.w, __shfl_xor(mx.w, off));
  }

  // pass 2: sum of exp
  float4 sm = make_float4(0.f, 0.f, 0.f, 0.f);
  for (int j = start + lane; j < end; j += 64) {
    int eid = csr_eid[j];
    int s = src[eid], et = e_feat[eid];
    float4 elv = *(const float4*)(el + s * kH);
    float4 ee = *(const float4*)(ee_sh + et * kH);
    sm.x += expf(lrelu(elv.x + erv.x + ee.x) - mx.x);
    sm.y += expf(lrelu(elv.y + erv.y + ee.y) - mx.y);
    sm.z += expf(lrelu(elv.z + erv.z + ee.z) - mx.z);
    sm.w += expf(lrelu(elv.w + erv.w + ee.w) - mx.w);
  }
#pragma unroll
  for (int off = 1; off < 64; off <<= 1) {
    sm.x += __shfl_xor(sm.x, off);
    sm.y += __shfl_xor(sm.y, off);
    sm.z += __shfl_xor(sm.z, off);
    sm.w += __shfl_xor(sm.w, off);
  }

  // pass 3: normalize (write a) + aggregate (lane covers dims 2l,2l+1; head = lane>>4)
  int h = lane >> 4;
  float m_h = get4(mx, h);
  float er_h = get4(erv, h);
  float rinv_h = 1.f / get4(sm, h);
  int d2 = lane * 2;
  float accx = 0.f, accy = 0.f;
  bool writer = (lane & 15) == 0;
  for (int j = start; j < end; ++j) {
    int eid = csr_eid[j];
    int s = src[eid], et = e_feat[eid];
    float e_h = lrelu(el[s * kH + h] + er_h + ee_sh[et * kH + h]);
    float a_h = expf(e_h - m_h) * rinv_h;
    if (writer) out_a[eid * kH + h] = a_h;
    int nt = node_types[s];
    float2 f2 = *(const float2*)(feat + s * kHD + d2);
    float2 c2 = *(const float2*)(fc_sh + nt * kHD + d2);
    accx += a_h * f2.x * c2.x;
    accy += a_h * f2.y * c2.y;
  }
  float2 hres = *(const float2*)(feat + node * kHD + d2);
  float2 o;
  o.x = accx + hres.x;
  o.y = accy + hres.y;
  *(float2*)(rst + node * kHD + d2) = o;
}

}  // namespace

extern "C" void kernel_launch(void* const* d_in, const int* in_sizes, int n_in,
                              void* d_out, int out_size, void* d_ws, size_t ws_size,
                              hipStream_t stream) {
  const float* feat = (const float*)d_in[0];
  const float* fc = (const float*)d_in[1];
  const float* edge_emb = (const float*)d_in[2];
  const float* W_e = (const float*)d_in[3];
  const float* attn_l = (const float*)d_in[4];
  const float* attn_r = (const float*)d_in[5];
  const float* attn_e = (const float*)d_in[6];
  const int* node_types = (const int*)d_in[7];
  const int* e_feat = (const int*)d_in[8];
  const int* src = (const int*)d_in[9];
  const int* dst = (const int*)d_in[10];
  int N = in_sizes[7];
  int E = in_sizes[8];

  char* ws = (char*)d_ws;
  size_t off = 0;
  auto alloc = [&](size_t bytes) -> void* {
    void* p = ws + off;
    off = (off + bytes + 255) & ~(size_t)255;
    return p;
  };
  float* ee_tab = (float*)alloc((size_t)kET * kH * sizeof(float));
  float* el = (float*)alloc((size_t)N * kH * sizeof(float));
  float* er = (float*)alloc((size_t)N * kH * sizeof(float));
  int* cnt = (int*)alloc((size_t)N * sizeof(int));
  int* ptr = (int*)alloc((size_t)(N + 1) * sizeof(int));
  int* cur = (int*)alloc((size_t)N * sizeof(int));
  int* scanbuf = (int*)alloc((size_t)N * sizeof(int));
  int* bsum = (int*)alloc(1024 * sizeof(int));
  int* csr_eid = (int*)alloc((size_t)E * sizeof(int));

  hipMemsetAsync(cnt, 0, (size_t)N * sizeof(int), stream);

  k_prep_ee<<<1, 64, 0, stream>>>(edge_emb, W_e, attn_e, ee_tab);
  k_node<<<(N + 3) / 4, 256, 0, stream>>>(feat, fc, attn_l, attn_r, node_types, el, er, N);
  k_hist<<<(E + 255) / 256, 256, 0, stream>>>(dst, cnt, E);
  int nb = (N + kScanB - 1) / kScanB;
  k_scan1<<<nb, kScanB, 0, stream>>>(cnt, scanbuf, bsum, N);
  k_scan2<<<1, 1024, 0, stream>>>(bsum, nb);
  k_scan3<<<nb, kScanB, 0, stream>>>(cnt, scanbuf, bsum, ptr, cur, N);
  k_scatter<<<(E + 255) / 256, 256, 0, stream>>>(dst, cur, csr_eid, E);

  float* rst = (float*)d_out;
  float* out_a = (float*)d_out + (size_t)N * kHD;
  k_fused<<<(N + 3) / 4, 256, 0, stream>>>(feat, fc, node_types, src, e_feat, el, er,
                                           ee_tab, ptr, csr_eid, rst, out_a, N);
}

// Round 2
// 565.758 us; speedup vs baseline: 1.3548x; 1.3548x over previous
//
#include <hip/hip_runtime.h>

namespace {
constexpr int kH = 4, kD = 32, kEF = 32, kNT = 4, kET = 8;
constexpr int kHD = kH * kD;  // 128
constexpr float kNegSlope = 0.2f;

typedef _Float16 half8 __attribute__((ext_vector_type(8)));
typedef _Float16 half2v __attribute__((ext_vector_type(2)));

__device__ __forceinline__ float lrelu(float x) { return x > 0.f ? x : kNegSlope * x; }

// Fused: zero cnt, compute ee table (block 0), per-node el/er/fs(fp16)
__global__ void __launch_bounds__(256) k_init(
    const float* __restrict__ feat, const float* __restrict__ fc,
    const float* __restrict__ edge_emb, const float* __restrict__ W_e,
    const float* __restrict__ attn_l, const float* __restrict__ attn_r,
    const float* __restrict__ attn_e, const int* __restrict__ node_types,
    float* __restrict__ el, float* __restrict__ er, _Float16* __restrict__ fs,
    float* __restrict__ ee_tab, int* __restrict__ cnt, int N) {
  int gid = blockIdx.x * blockDim.x + threadIdx.x;
  if (gid < N) cnt[gid] = 0;

  if (blockIdx.x == 0 && threadIdx.x < kET * kH) {
    int et = threadIdx.x / kH, h = threadIdx.x % kH;
    float acc = 0.f;
    for (int f = 0; f < kEF; ++f) {
      const float* wrow = W_e + (h * kEF + f) * kEF;
      const float* erow = edge_emb + et * kEF;
      float emb = 0.f;
      for (int k = 0; k < kEF; ++k) emb += erow[k] * wrow[k];
      acc += emb * attn_e[h * kEF + f];
    }
    ee_tab[et * kH + h] = acc;
  }

  int node = gid >> 6;
  int lane = threadIdx.x & 63;
  if (node >= N) return;
  int nt = node_types[node];
  float2 f2 = *(const float2*)(feat + node * kHD + lane * 2);
  float2 c2 = *(const float2*)(fc + nt * kHD + lane * 2);
  float2 al = *(const float2*)(attn_l + lane * 2);
  float2 ar = *(const float2*)(attn_r + lane * 2);
  float fx = f2.x * c2.x, fy = f2.y * c2.y;
  half2v hv;
  hv.x = (_Float16)fx;
  hv.y = (_Float16)fy;
  *(half2v*)(fs + node * kHD + lane * 2) = hv;
  float pl = fx * al.x + fy * al.y;
  float pr = fx * ar.x + fy * ar.y;
#pragma unroll
  for (int off = 1; off < 16; off <<= 1) {  // reduce within 16-lane head groups
    pl += __shfl_xor(pl, off);
    pr += __shfl_xor(pr, off);
  }
  if ((lane & 15) == 0) {
    int h = lane >> 4;
    el[node * kH + h] = pl;
    er[node * kH + h] = pr;
  }
}

__global__ void k_hist(const int* __restrict__ dst, int* __restrict__ cnt, int E) {
  int i = blockIdx.x * blockDim.x + threadIdx.x;
  if (i < E) atomicAdd(&cnt[dst[i]], 1);
}

constexpr int kScanB = 256;

__global__ void k_scan1(const int* __restrict__ cnt, int* __restrict__ scanbuf,
                        int* __restrict__ bsum, int N) {
  __shared__ int sh[kScanB];
  int i = blockIdx.x * kScanB + threadIdx.x;
  int x = (i < N) ? cnt[i] : 0;
  sh[threadIdx.x] = x;
  __syncthreads();
  for (int off = 1; off < kScanB; off <<= 1) {
    int v = (threadIdx.x >= off) ? sh[threadIdx.x - off] : 0;
    __syncthreads();
    sh[threadIdx.x] += v;
    __syncthreads();
  }
  if (i < N) scanbuf[i] = sh[threadIdx.x];
  if (threadIdx.x == kScanB - 1) bsum[blockIdx.x] = sh[kScanB - 1];
}

__global__ void k_scan2(int* __restrict__ bsum, int nb) {
  __shared__ int sh[1024];
  int t = threadIdx.x;
  int x = (t < nb) ? bsum[t] : 0;
  sh[t] = x;
  __syncthreads();
  for (int off = 1; off < 1024; off <<= 1) {
    int v = (t >= off) ? sh[t - off] : 0;
    __syncthreads();
    sh[t] += v;
    __syncthreads();
  }
  if (t < nb) bsum[t] = sh[t];  // inclusive
}

__global__ void k_scan3(const int* __restrict__ cnt, const int* __restrict__ scanbuf,
                        const int* __restrict__ bsum, int* __restrict__ ptr,
                        int* __restrict__ cur, int N) {
  int i = blockIdx.x * kScanB + threadIdx.x;
  if (i >= N) return;
  int incl = scanbuf[i] + (blockIdx.x ? bsum[blockIdx.x - 1] : 0);
  int excl = incl - cnt[i];
  ptr[i] = excl;
  cur[i] = excl;
  if (i == N - 1) ptr[N] = incl;
}

__global__ void k_scatter(const int* __restrict__ dst, int* __restrict__ cur,
                          int* __restrict__ csr_eid, int E) {
  int i = blockIdx.x * blockDim.x + threadIdx.x;
  if (i < E) {
    int p = atomicAdd(&cur[dst[i]], 1);
    csr_eid[p] = i;
  }
}

// one wave per dst node. Main loop: 4 edges x 16 lanes, unnormalized exp
// accumulation (softmax shift-invariance, scores are O(1)); then scale by 1/s.
// Second light edge-parallel loop computes & writes a with float4 stores.
__global__ void __launch_bounds__(256) k_fused(
    const _Float16* __restrict__ fs, const float* __restrict__ feat,
    const int* __restrict__ src, const int* __restrict__ e_feat,
    const float* __restrict__ el, const float* __restrict__ er,
    const float* __restrict__ ee_tab, const int* __restrict__ ptr,
    const int* __restrict__ csr_eid, float* __restrict__ rst,
    float* __restrict__ out_a, int N) {
  __shared__ __align__(16) float ee_sh[kET * kH];
  if (threadIdx.x < kET * kH) ee_sh[threadIdx.x] = ee_tab[threadIdx.x];
  __syncthreads();
  int lane = threadIdx.x & 63;
  int node = blockIdx.x * (blockDim.x >> 6) + (threadIdx.x >> 6);
  if (node >= N) return;
  int start = ptr[node], end = ptr[node + 1];
  float4 erv = *(const float4*)(er + node * kH);

  int g = lane >> 4;        // edge slot within wave (4 edges in flight)
  int q = lane & 15;        // dim-lane within edge: dims [q*8, q*8+8)
  int head = q >> 2;
  int d0 = q * 8;
  float er_h = head == 0 ? erv.x : head == 1 ? erv.y : head == 2 ? erv.z : erv.w;

  float sm = 0.f;
  float acc[8];
#pragma unroll
  for (int k = 0; k < 8; ++k) acc[k] = 0.f;

  for (int j = start + g; j < end; j += 4) {
    int eid = csr_eid[j];
    int s = src[eid];
    int et = e_feat[eid];
    float e_h = lrelu(el[s * kH + head] + er_h + ee_sh[et * kH + head]);
    float ex = __expf(e_h);
    sm += ex;
    half8 hv = *(const half8*)(fs + s * kHD + d0);
#pragma unroll
    for (int k = 0; k < 8; ++k) acc[k] += ex * (float)hv[k];
  }
  // reduce across the 4 edge-groups (lanes differing in bits 4,5)
  sm += __shfl_xor(sm, 16);
  sm += __shfl_xor(sm, 32);
#pragma unroll
  for (int k = 0; k < 8; ++k) {
    acc[k] += __shfl_xor(acc[k], 16);
    acc[k] += __shfl_xor(acc[k], 32);
  }
  float rinv = sm > 0.f ? 1.f / sm : 0.f;  // guard degree-0 nodes

  if (g == 0) {  // lanes 0..15 write the 512B rst row
    float4 o0, o1;
    const float* fr = feat + node * kHD + d0;
    o0.x = acc[0] * rinv + fr[0];
    o0.y = acc[1] * rinv + fr[1];
    o0.z = acc[2] * rinv + fr[2];
    o0.w = acc[3] * rinv + fr[3];
    o1.x = acc[4] * rinv + fr[4];
    o1.y = acc[5] * rinv + fr[5];
    o1.z = acc[6] * rinv + fr[6];
    o1.w = acc[7] * rinv + fr[7];
    *(float4*)(rst + node * kHD + d0) = o0;
    *(float4*)(rst + node * kHD + d0 + 4) = o1;
  }

  // broadcast per-head 1/s to all lanes (lanes 0,4,8,12 hold heads 0..3)
  float rv0 = __shfl(rinv, 0);
  float rv1 = __shfl(rinv, 4);
  float rv2 = __shfl(rinv, 8);
  float rv3 = __shfl(rinv, 12);

  // edge-parallel a computation + float4 store
  for (int j = start + lane; j < end; j += 64) {
    int eid = csr_eid[j];
    int s = src[eid];
    int et = e_feat[eid];
    float4 elv = *(const float4*)(el + s * kH);
    float4 ee = *(const float4*)(ee_sh + et * kH);
    float4 a;
    a.x = __expf(lrelu(elv.x + erv.x + ee.x)) * rv0;
    a.y = __expf(lrelu(elv.y + erv.y + ee.y)) * rv1;
    a.z = __expf(lrelu(elv.z + erv.z + ee.z)) * rv2;
    a.w = __expf(lrelu(elv.w + erv.w + ee.w)) * rv3;
    *(float4*)(out_a + (size_t)eid * kH) = a;
  }
}

}  // namespace

extern "C" void kernel_launch(void* const* d_in, const int* in_sizes, int n_in,
                              void* d_out, int out_size, void* d_ws, size_t ws_size,
                              hipStream_t stream) {
  const float* feat = (const float*)d_in[0];
  const float* fc = (const float*)d_in[1];
  const float* edge_emb = (const float*)d_in[2];
  const float* W_e = (const float*)d_in[3];
  const float* attn_l = (const float*)d_in[4];
  const float* attn_r = (const float*)d_in[5];
  const float* attn_e = (const float*)d_in[6];
  const int* node_types = (const int*)d_in[7];
  const int* e_feat = (const int*)d_in[8];
  const int* src = (const int*)d_in[9];
  const int* dst = (const int*)d_in[10];
  int N = in_sizes[7];
  int E = in_sizes[8];

  char* ws = (char*)d_ws;
  size_t off = 0;
  auto alloc = [&](size_t bytes) -> void* {
    void* p = ws + off;
    off = (off + bytes + 255) & ~(size_t)255;
    return p;
  };
  float* ee_tab = (float*)alloc((size_t)kET * kH * sizeof(float));
  float* el = (float*)alloc((size_t)N * kH * sizeof(float));
  float* er = (float*)alloc((size_t)N * kH * sizeof(float));
  _Float16* fs = (_Float16*)alloc((size_t)N * kHD * sizeof(_Float16));
  int* cnt = (int*)alloc((size_t)N * sizeof(int));
  int* ptr = (int*)alloc((size_t)(N + 1) * sizeof(int));
  int* cur = (int*)alloc((size_t)N * sizeof(int));
  int* scanbuf = (int*)alloc((size_t)N * sizeof(int));
  int* bsum = (int*)alloc(1024 * sizeof(int));
  int* csr_eid = (int*)alloc((size_t)E * sizeof(int));

  k_init<<<(N + 3) / 4, 256, 0, stream>>>(feat, fc, edge_emb, W_e, attn_l, attn_r,
                                          attn_e, node_types, el, er, fs, ee_tab, cnt, N);
  k_hist<<<(E + 255) / 256, 256, 0, stream>>>(dst, cnt, E);
  int nb = (N + kScanB - 1) / kScanB;
  k_scan1<<<nb, kScanB, 0, stream>>>(cnt, scanbuf, bsum, N);
  k_scan2<<<1, 1024, 0, stream>>>(bsum, nb);
  k_scan3<<<nb, kScanB, 0, stream>>>(cnt, scanbuf, bsum, ptr, cur, N);
  k_scatter<<<(E + 255) / 256, 256, 0, stream>>>(dst, cur, csr_eid, E);

  float* rst = (float*)d_out;
  float* out_a = (float*)d_out + (size_t)N * kHD;
  k_fused<<<(N + 3) / 4, 256, 0, stream>>>(fs, feat, src, e_feat, el, er, ee_tab, ptr,
                                           csr_eid, rst, out_a, N);
}

// Round 3
// 352.026 us; speedup vs baseline: 2.1774x; 1.6071x over previous
//
#include <hip/hip_runtime.h>

namespace {
constexpr int kH = 4, kD = 32, kEF = 32, kNT = 4, kET = 8;
constexpr int kHD = kH * kD;  // 128
constexpr float kNegSlope = 0.2f;

typedef _Float16 half16 __attribute__((ext_vector_type(16)));
typedef _Float16 half2v __attribute__((ext_vector_type(2)));

__device__ __forceinline__ float lrelu(float x) { return x > 0.f ? x : kNegSlope * x; }

// Fused: ee table (block 0), per-node el/er/fs(fp16), per-edge rank atomics.
// cnt must be zeroed before this kernel (hipMemsetAsync).
__global__ void __launch_bounds__(256) k_init(
    const float* __restrict__ feat, const float* __restrict__ fc,
    const float* __restrict__ edge_emb, const float* __restrict__ W_e,
    const float* __restrict__ attn_l, const float* __restrict__ attn_r,
    const float* __restrict__ attn_e, const int* __restrict__ node_types,
    const int* __restrict__ dst,
    float* __restrict__ el, float* __restrict__ er, _Float16* __restrict__ fs,
    float* __restrict__ ee_tab, int* __restrict__ cnt, int* __restrict__ rank,
    int N, int E) {
  if (blockIdx.x == 0 && threadIdx.x < kET * kH) {
    int et = threadIdx.x / kH, h = threadIdx.x % kH;
    float acc = 0.f;
    for (int f = 0; f < kEF; ++f) {
      const float* wrow = W_e + (h * kEF + f) * kEF;
      const float* erow = edge_emb + et * kEF;
      float emb = 0.f;
      for (int k = 0; k < kEF; ++k) emb += erow[k] * wrow[k];
      acc += emb * attn_e[h * kEF + f];
    }
    ee_tab[et * kH + h] = acc;
  }

  // edge rank: each block takes a contiguous chunk (spreads atomics evenly)
  int per = (E + gridDim.x - 1) / gridDim.x;
  int e0 = blockIdx.x * per;
  int e1 = min(e0 + per, E);
  for (int i = e0 + threadIdx.x; i < e1; i += blockDim.x) {
    rank[i] = atomicAdd(&cnt[dst[i]], 1);
  }

  int gid = blockIdx.x * blockDim.x + threadIdx.x;
  int node = gid >> 6;
  int lane = threadIdx.x & 63;
  if (node >= N) return;
  int nt = node_types[node];
  float2 f2 = *(const float2*)(feat + node * kHD + lane * 2);
  float2 c2 = *(const float2*)(fc + nt * kHD + lane * 2);
  float2 al = *(const float2*)(attn_l + lane * 2);
  float2 ar = *(const float2*)(attn_r + lane * 2);
  float fx = f2.x * c2.x, fy = f2.y * c2.y;
  half2v hv;
  hv.x = (_Float16)fx;
  hv.y = (_Float16)fy;
  *(half2v*)(fs + node * kHD + lane * 2) = hv;
  float pl = fx * al.x + fy * al.y;
  float pr = fx * ar.x + fy * ar.y;
#pragma unroll
  for (int off = 1; off < 16; off <<= 1) {
    pl += __shfl_xor(pl, off);
    pr += __shfl_xor(pr, off);
  }
  if ((lane & 15) == 0) {
    int h = lane >> 4;
    el[node * kH + h] = pl;
    er[node * kH + h] = pr;
  }
}

constexpr int kScanB = 256;

__global__ void k_scan1(const int* __restrict__ cnt, int* __restrict__ scanbuf,
                        int* __restrict__ bsum, int N) {
  __shared__ int sh[kScanB];
  int i = blockIdx.x * kScanB + threadIdx.x;
  int x = (i < N) ? cnt[i] : 0;
  sh[threadIdx.x] = x;
  __syncthreads();
  for (int off = 1; off < kScanB; off <<= 1) {
    int v = (threadIdx.x >= off) ? sh[threadIdx.x - off] : 0;
    __syncthreads();
    sh[threadIdx.x] += v;
    __syncthreads();
  }
  if (i < N) scanbuf[i] = sh[threadIdx.x];
  if (threadIdx.x == kScanB - 1) bsum[blockIdx.x] = sh[kScanB - 1];
}

__global__ void k_scan2(int* __restrict__ bsum, int nb) {
  __shared__ int sh[1024];
  int t = threadIdx.x;
  int x = (t < nb) ? bsum[t] : 0;
  sh[t] = x;
  __syncthreads();
  for (int off = 1; off < 1024; off <<= 1) {
    int v = (t >= off) ? sh[t - off] : 0;
    __syncthreads();
    sh[t] += v;
    __syncthreads();
  }
  if (t < nb) bsum[t] = sh[t];  // inclusive
}

__global__ void k_scan3(const int* __restrict__ cnt, const int* __restrict__ scanbuf,
                        const int* __restrict__ bsum, int* __restrict__ ptr, int N) {
  int i = blockIdx.x * kScanB + threadIdx.x;
  if (i >= N) return;
  int incl = scanbuf[i] + (blockIdx.x ? bsum[blockIdx.x - 1] : 0);
  ptr[i] = incl - cnt[i];
  if (i == N - 1) ptr[N] = incl;
}

// atomic-free scatter: csr[ptr[dst]+rank] = src | (e_feat<<20)
__global__ void k_scatter(const int* __restrict__ dst, const int* __restrict__ src,
                          const int* __restrict__ e_feat, const int* __restrict__ rank,
                          const int* __restrict__ ptr, int* __restrict__ csr, int E) {
  int i = blockIdx.x * blockDim.x + threadIdx.x;
  if (i < E) {
    int p = ptr[dst[i]] + rank[i];
    csr[p] = src[i] | (e_feat[i] << 20);
  }
}

// one wave per dst node, 8 edges x 8 lanes (16 dims / lane).
// Unnormalized exp accumulation (shift-invariant softmax, scores O(1)),
// scale by 1/s afterwards. Writes rst row + per-node rinv[4].
__global__ void __launch_bounds__(256) k_fused(
    const _Float16* __restrict__ fs, const float* __restrict__ feat,
    const float* __restrict__ el, const float* __restrict__ er,
    const float* __restrict__ ee_tab, const int* __restrict__ ptr,
    const int* __restrict__ csr, float* __restrict__ rst,
    float* __restrict__ rinv_buf, int N) {
  __shared__ __align__(16) float ee_sh[kET * kH];
  if (threadIdx.x < kET * kH) ee_sh[threadIdx.x] = ee_tab[threadIdx.x];
  __syncthreads();
  int lane = threadIdx.x & 63;
  int node = blockIdx.x * (blockDim.x >> 6) + (threadIdx.x >> 6);
  if (node >= N) return;
  int start = ptr[node], end = ptr[node + 1];

  int g = lane >> 3;   // edge slot (8 edges in flight)
  int q = lane & 7;    // dim-lane: dims [q*16, q*16+16)
  int head = q >> 1;
  float er_h = er[node * kH + head];

  float sm = 0.f;
  float acc[16];
#pragma unroll
  for (int k = 0; k < 16; ++k) acc[k] = 0.f;

  for (int j = start + g; j < end; j += 8) {
    int pk = csr[j];
    int s = pk & 0xFFFFF;
    int et = pk >> 20;
    float e_h = lrelu(el[s * kH + head] + er_h + ee_sh[et * kH + head]);
    float ex = __expf(e_h);
    sm += ex;
    half16 hv = *(const half16*)(fs + s * kHD + q * 16);
#pragma unroll
    for (int k = 0; k < 16; ++k) acc[k] += ex * (float)hv[k];
  }
  // reduce across the 8 edge-groups (lane bits 3,4,5)
  sm += __shfl_xor(sm, 8);
  sm += __shfl_xor(sm, 16);
  sm += __shfl_xor(sm, 32);
#pragma unroll
  for (int k = 0; k < 16; ++k) {
    acc[k] += __shfl_xor(acc[k], 8);
    acc[k] += __shfl_xor(acc[k], 16);
    acc[k] += __shfl_xor(acc[k], 32);
  }
  float rinv = sm > 0.f ? 1.f / sm : 0.f;  // guard degree-0 nodes

  if (g == 0) {  // lanes 0..7 write the 512B rst row (16 floats each)
    const float* fr = feat + node * kHD + q * 16;
    float* out = rst + node * kHD + q * 16;
#pragma unroll
    for (int r = 0; r < 4; ++r) {
      float4 o;
      o.x = acc[r * 4 + 0] * rinv + fr[r * 4 + 0];
      o.y = acc[r * 4 + 1] * rinv + fr[r * 4 + 1];
      o.z = acc[r * 4 + 2] * rinv + fr[r * 4 + 2];
      o.w = acc[r * 4 + 3] * rinv + fr[r * 4 + 3];
      *(float4*)(out + r * 4) = o;
    }
    if ((q & 1) == 0) rinv_buf[node * kH + head] = rinv;
  }
}

// edge-parallel a computation in ORIGINAL edge order: coalesced float4 stores
__global__ void k_post(const int* __restrict__ src, const int* __restrict__ dst,
                       const int* __restrict__ e_feat, const float* __restrict__ el,
                       const float* __restrict__ er, const float* __restrict__ ee_tab,
                       const float* __restrict__ rinv_buf, float* __restrict__ out_a,
                       int E) {
  int i = blockIdx.x * blockDim.x + threadIdx.x;
  if (i >= E) return;
  int s = src[i], d = dst[i], et = e_feat[i];
  float4 elv = *(const float4*)(el + s * kH);
  float4 erv = *(const float4*)(er + d * kH);
  float4 ee = *(const float4*)(ee_tab + et * kH);
  float4 rv = *(const float4*)(rinv_buf + d * kH);
  float4 a;
  a.x = __expf(lrelu(elv.x + erv.x + ee.x)) * rv.x;
  a.y = __expf(lrelu(elv.y + erv.y + ee.y)) * rv.y;
  a.z = __expf(lrelu(elv.z + erv.z + ee.z)) * rv.z;
  a.w = __expf(lrelu(elv.w + erv.w + ee.w)) * rv.w;
  *(float4*)(out_a + (size_t)i * kH) = a;
}

}  // namespace

extern "C" void kernel_launch(void* const* d_in, const int* in_sizes, int n_in,
                              void* d_out, int out_size, void* d_ws, size_t ws_size,
                              hipStream_t stream) {
  const float* feat = (const float*)d_in[0];
  const float* fc = (const float*)d_in[1];
  const float* edge_emb = (const float*)d_in[2];
  const float* W_e = (const float*)d_in[3];
  const float* attn_l = (const float*)d_in[4];
  const float* attn_r = (const float*)d_in[5];
  const float* attn_e = (const float*)d_in[6];
  const int* node_types = (const int*)d_in[7];
  const int* e_feat = (const int*)d_in[8];
  const int* src = (const int*)d_in[9];
  const int* dst = (const int*)d_in[10];
  int N = in_sizes[7];
  int E = in_sizes[8];

  char* ws = (char*)d_ws;
  size_t off = 0;
  auto alloc = [&](size_t bytes) -> void* {
    void* p = ws + off;
    off = (off + bytes + 255) & ~(size_t)255;
    return p;
  };
  float* ee_tab = (float*)alloc((size_t)kET * kH * sizeof(float));
  float* el = (float*)alloc((size_t)N * kH * sizeof(float));
  float* er = (float*)alloc((size_t)N * kH * sizeof(float));
  float* rinv_buf = (float*)alloc((size_t)N * kH * sizeof(float));
  _Float16* fs = (_Float16*)alloc((size_t)N * kHD * sizeof(_Float16));
  int* cnt = (int*)alloc((size_t)N * sizeof(int));
  int* ptr = (int*)alloc((size_t)(N + 1) * sizeof(int));
  int* rank = (int*)alloc((size_t)E * sizeof(int));
  int* scanbuf = (int*)alloc((size_t)N * sizeof(int));
  int* bsum = (int*)alloc(1024 * sizeof(int));
  int* csr = (int*)alloc((size_t)E * sizeof(int));

  hipMemsetAsync(cnt, 0, (size_t)N * sizeof(int), stream);

  k_init<<<(N + 3) / 4, 256, 0, stream>>>(feat, fc, edge_emb, W_e, attn_l, attn_r,
                                          attn_e, node_types, dst, el, er, fs, ee_tab,
                                          cnt, rank, N, E);
  int nb = (N + kScanB - 1) / kScanB;
  k_scan1<<<nb, kScanB, 0, stream>>>(cnt, scanbuf, bsum, N);
  k_scan2<<<1, 1024, 0, stream>>>(bsum, nb);
  k_scan3<<<nb, kScanB, 0, stream>>>(cnt, scanbuf, bsum, ptr, N);
  k_scatter<<<(E + 255) / 256, 256, 0, stream>>>(dst, src, e_feat, rank, ptr, csr, E);

  float* rst = (float*)d_out;
  float* out_a = (float*)d_out + (size_t)N * kHD;
  k_fused<<<(N + 3) / 4, 256, 0, stream>>>(fs, feat, el, er, ee_tab, ptr, csr, rst,
                                           rinv_buf, N);
  k_post<<<(E + 255) / 256, 256, 0, stream>>>(src, dst, e_feat, el, er, ee_tab,
                                              rinv_buf, out_a, E);
}

// Round 4
// 351.751 us; speedup vs baseline: 2.1791x; 1.0008x over previous
//
#include <hip/hip_runtime.h>

namespace {
constexpr int kH = 4, kD = 32, kEF = 32, kNT = 4, kET = 8;
constexpr int kHD = kH * kD;  // 128
constexpr float kNegSlope = 0.2f;
constexpr int kCntStride = 16;  // one counter per 64B line (atomic contention)

typedef _Float16 half16 __attribute__((ext_vector_type(16)));
typedef _Float16 half2v __attribute__((ext_vector_type(2)));

__device__ __forceinline__ float lrelu(float x) { return x > 0.f ? x : kNegSlope * x; }

// Fused: ee table (block 0), per-node el/er/fs(fp16), per-edge rank atomics.
// cnt (padded, stride 16) must be zeroed before this kernel.
__global__ void __launch_bounds__(256) k_init(
    const float* __restrict__ feat, const float* __restrict__ fc,
    const float* __restrict__ edge_emb, const float* __restrict__ W_e,
    const float* __restrict__ attn_l, const float* __restrict__ attn_r,
    const float* __restrict__ attn_e, const int* __restrict__ node_types,
    const int* __restrict__ dst,
    float* __restrict__ el, float* __restrict__ er, _Float16* __restrict__ fs,
    float* __restrict__ ee_tab, int* __restrict__ cnt, int* __restrict__ rank,
    int N, int E) {
  if (blockIdx.x == 0 && threadIdx.x < kET * kH) {
    int et = threadIdx.x / kH, h = threadIdx.x % kH;
    float acc = 0.f;
    for (int f = 0; f < kEF; ++f) {
      const float* wrow = W_e + (h * kEF + f) * kEF;
      const float* erow = edge_emb + et * kEF;
      float emb = 0.f;
      for (int k = 0; k < kEF; ++k) emb += erow[k] * wrow[k];
      acc += emb * attn_e[h * kEF + f];
    }
    ee_tab[et * kH + h] = acc;
  }

  // edge rank: each block takes a contiguous chunk (spreads atomics evenly)
  int per = (E + gridDim.x - 1) / gridDim.x;
  int e0 = blockIdx.x * per;
  int e1 = min(e0 + per, E);
  for (int i = e0 + threadIdx.x; i < e1; i += blockDim.x) {
    rank[i] = atomicAdd(&cnt[dst[i] * kCntStride], 1);
  }

  int gid = blockIdx.x * blockDim.x + threadIdx.x;
  int node = gid >> 6;
  int lane = threadIdx.x & 63;
  if (node >= N) return;
  int nt = node_types[node];
  float2 f2 = *(const float2*)(feat + node * kHD + lane * 2);
  float2 c2 = *(const float2*)(fc + nt * kHD + lane * 2);
  float2 al = *(const float2*)(attn_l + lane * 2);
  float2 ar = *(const float2*)(attn_r + lane * 2);
  float fx = f2.x * c2.x, fy = f2.y * c2.y;
  half2v hv;
  hv.x = (_Float16)fx;
  hv.y = (_Float16)fy;
  *(half2v*)(fs + node * kHD + lane * 2) = hv;
  float pl = fx * al.x + fy * al.y;
  float pr = fx * ar.x + fy * ar.y;
#pragma unroll
  for (int off = 1; off < 16; off <<= 1) {
    pl += __shfl_xor(pl, off);
    pr += __shfl_xor(pr, off);
  }
  if ((lane & 15) == 0) {
    int h = lane >> 4;
    el[node * kH + h] = pl;
    er[node * kH + h] = pr;
  }
}

constexpr int kScanB = 256;

__global__ void k_scan1(const int* __restrict__ cnt, int* __restrict__ scanbuf,
                        int* __restrict__ bsum, int N) {
  __shared__ int sh[kScanB];
  int i = blockIdx.x * kScanB + threadIdx.x;
  int x = (i < N) ? cnt[i * kCntStride] : 0;
  sh[threadIdx.x] = x;
  __syncthreads();
  for (int off = 1; off < kScanB; off <<= 1) {
    int v = (threadIdx.x >= off) ? sh[threadIdx.x - off] : 0;
    __syncthreads();
    sh[threadIdx.x] += v;
    __syncthreads();
  }
  if (i < N) scanbuf[i] = sh[threadIdx.x];
  if (threadIdx.x == kScanB - 1) bsum[blockIdx.x] = sh[kScanB - 1];
}

__global__ void k_scan2(int* __restrict__ bsum, int nb) {
  __shared__ int sh[1024];
  int t = threadIdx.x;
  int x = (t < nb) ? bsum[t] : 0;
  sh[t] = x;
  __syncthreads();
  for (int off = 1; off < 1024; off <<= 1) {
    int v = (t >= off) ? sh[t - off] : 0;
    __syncthreads();
    sh[t] += v;
    __syncthreads();
  }
  if (t < nb) bsum[t] = sh[t];  // inclusive
}

__global__ void k_scan3(const int* __restrict__ cnt, const int* __restrict__ scanbuf,
                        const int* __restrict__ bsum, int* __restrict__ ptr, int N) {
  int i = blockIdx.x * kScanB + threadIdx.x;
  if (i >= N) return;
  int incl = scanbuf[i] + (blockIdx.x ? bsum[blockIdx.x - 1] : 0);
  ptr[i] = incl - cnt[i * kCntStride];
  if (i == N - 1) ptr[N] = incl;
}

// atomic-free scatter: csr[ptr[dst]+rank] = src | (e_feat<<20)
__global__ void k_scatter(const int* __restrict__ dst, const int* __restrict__ src,
                          const int* __restrict__ e_feat, const int* __restrict__ rank,
                          const int* __restrict__ ptr, int* __restrict__ csr, int E) {
  int i = blockIdx.x * blockDim.x + threadIdx.x;
  if (i < E) {
    int p = ptr[dst[i]] + rank[i];
    csr[p] = src[i] | (e_feat[i] << 20);
  }
}

// one wave per dst node, 8 edges x 8 lanes (16 dims / lane).
// Unnormalized exp accumulation (shift-invariant softmax, scores O(1)),
// packed fp16 FMA inner product, scale by 1/s afterwards.
__global__ void __launch_bounds__(256) k_fused(
    const _Float16* __restrict__ fs, const float* __restrict__ feat,
    const float* __restrict__ el, const float* __restrict__ er,
    const float* __restrict__ ee_tab, const int* __restrict__ ptr,
    const int* __restrict__ csr, float* __restrict__ rst,
    float* __restrict__ rinv_buf, int N) {
  __shared__ __align__(16) float ee_sh[kET * kH];
  if (threadIdx.x < kET * kH) ee_sh[threadIdx.x] = ee_tab[threadIdx.x];
  __syncthreads();
  int lane = threadIdx.x & 63;
  int node = blockIdx.x * (blockDim.x >> 6) + (threadIdx.x >> 6);
  if (node >= N) return;
  int start = ptr[node], end = ptr[node + 1];

  int g = lane >> 3;   // edge slot (8 edges in flight)
  int q = lane & 7;    // dim-lane: dims [q*16, q*16+16)
  int head = q >> 1;
  float er_h = er[node * kH + head];

  float sm = 0.f;
  half16 acch;
#pragma unroll
  for (int k = 0; k < 16; ++k) acch[k] = (_Float16)0.f;

  for (int j = start + g; j < end; j += 8) {
    int pk = csr[j];
    int s = pk & 0xFFFFF;
    int et = pk >> 20;
    float e_h = lrelu(el[s * kH + head] + er_h + ee_sh[et * kH + head]);
    float ex = __expf(e_h);
    sm += ex;
    half16 hv = *(const half16*)(fs + s * kHD + q * 16);
    acch += hv * (_Float16)ex;  // v_pk_fma_f16 x8
  }
  float acc[16];
#pragma unroll
  for (int k = 0; k < 16; ++k) acc[k] = (float)acch[k];
  // reduce across the 8 edge-groups (lane bits 3,4,5) in fp32
  sm += __shfl_xor(sm, 8);
  sm += __shfl_xor(sm, 16);
  sm += __shfl_xor(sm, 32);
#pragma unroll
  for (int k = 0; k < 16; ++k) {
    acc[k] += __shfl_xor(acc[k], 8);
    acc[k] += __shfl_xor(acc[k], 16);
    acc[k] += __shfl_xor(acc[k], 32);
  }
  float rinv = sm > 0.f ? 1.f / sm : 0.f;  // guard degree-0 nodes

  if (g == 0) {  // lanes 0..7 write the 512B rst row (16 floats each)
    const float* fr = feat + node * kHD + q * 16;
    float* out = rst + node * kHD + q * 16;
#pragma unroll
    for (int r = 0; r < 4; ++r) {
      float4 o;
      o.x = acc[r * 4 + 0] * rinv + fr[r * 4 + 0];
      o.y = acc[r * 4 + 1] * rinv + fr[r * 4 + 1];
      o.z = acc[r * 4 + 2] * rinv + fr[r * 4 + 2];
      o.w = acc[r * 4 + 3] * rinv + fr[r * 4 + 3];
      *(float4*)(out + r * 4) = o;
    }
    if ((q & 1) == 0) rinv_buf[node * kH + head] = rinv;
  }
}

// edge-parallel a computation in ORIGINAL edge order: coalesced float4 stores
__global__ void k_post(const int* __restrict__ src, const int* __restrict__ dst,
                       const int* __restrict__ e_feat, const float* __restrict__ el,
                       const float* __restrict__ er, const float* __restrict__ ee_tab,
                       const float* __restrict__ rinv_buf, float* __restrict__ out_a,
                       int E) {
  int i = blockIdx.x * blockDim.x + threadIdx.x;
  if (i >= E) return;
  int s = src[i], d = dst[i], et = e_feat[i];
  float4 elv = *(const float4*)(el + s * kH);
  float4 erv = *(const float4*)(er + d * kH);
  float4 ee = *(const float4*)(ee_tab + et * kH);
  float4 rv = *(const float4*)(rinv_buf + d * kH);
  float4 a;
  a.x = __expf(lrelu(elv.x + erv.x + ee.x)) * rv.x;
  a.y = __expf(lrelu(elv.y + erv.y + ee.y)) * rv.y;
  a.z = __expf(lrelu(elv.z + erv.z + ee.z)) * rv.z;
  a.w = __expf(lrelu(elv.w + erv.w + ee.w)) * rv.w;
  *(float4*)(out_a + (size_t)i * kH) = a;
}

}  // namespace

extern "C" void kernel_launch(void* const* d_in, const int* in_sizes, int n_in,
                              void* d_out, int out_size, void* d_ws, size_t ws_size,
                              hipStream_t stream) {
  const float* feat = (const float*)d_in[0];
  const float* fc = (const float*)d_in[1];
  const float* edge_emb = (const float*)d_in[2];
  const float* W_e = (const float*)d_in[3];
  const float* attn_l = (const float*)d_in[4];
  const float* attn_r = (const float*)d_in[5];
  const float* attn_e = (const float*)d_in[6];
  const int* node_types = (const int*)d_in[7];
  const int* e_feat = (const int*)d_in[8];
  const int* src = (const int*)d_in[9];
  const int* dst = (const int*)d_in[10];
  int N = in_sizes[7];
  int E = in_sizes[8];

  char* ws = (char*)d_ws;
  size_t off = 0;
  auto alloc = [&](size_t bytes) -> void* {
    void* p = ws + off;
    off = (off + bytes + 255) & ~(size_t)255;
    return p;
  };
  float* ee_tab = (float*)alloc((size_t)kET * kH * sizeof(float));
  float* el = (float*)alloc((size_t)N * kH * sizeof(float));
  float* er = (float*)alloc((size_t)N * kH * sizeof(float));
  float* rinv_buf = (float*)alloc((size_t)N * kH * sizeof(float));
  _Float16* fs = (_Float16*)alloc((size_t)N * kHD * sizeof(_Float16));
  int* cnt = (int*)alloc((size_t)N * kCntStride * sizeof(int));
  int* ptr = (int*)alloc((size_t)(N + 1) * sizeof(int));
  int* rank = (int*)alloc((size_t)E * sizeof(int));
  int* scanbuf = (int*)alloc((size_t)N * sizeof(int));
  int* bsum = (int*)alloc(1024 * sizeof(int));
  int* csr = (int*)alloc((size_t)E * sizeof(int));

  hipMemsetAsync(cnt, 0, (size_t)N * kCntStride * sizeof(int), stream);

  k_init<<<(N + 3) / 4, 256, 0, stream>>>(feat, fc, edge_emb, W_e, attn_l, attn_r,
                                          attn_e, node_types, dst, el, er, fs, ee_tab,
                                          cnt, rank, N, E);
  int nb = (N + kScanB - 1) / kScanB;
  k_scan1<<<nb, kScanB, 0, stream>>>(cnt, scanbuf, bsum, N);
  k_scan2<<<1, 1024, 0, stream>>>(bsum, nb);
  k_scan3<<<nb, kScanB, 0, stream>>>(cnt, scanbuf, bsum, ptr, N);
  k_scatter<<<(E + 255) / 256, 256, 0, stream>>>(dst, src, e_feat, rank, ptr, csr, E);

  float* rst = (float*)d_out;
  float* out_a = (float*)d_out + (size_t)N * kHD;
  k_fused<<<(N + 3) / 4, 256, 0, stream>>>(fs, feat, el, er, ee_tab, ptr, csr, rst,
                                           rinv_buf, N);
  k_post<<<(E + 255) / 256, 256, 0, stream>>>(src, dst, e_feat, el, er, ee_tab,
                                              rinv_buf, out_a, E);
}

// Round 5
// 335.890 us; speedup vs baseline: 2.2820x; 1.0472x over previous
//
#include <hip/hip_runtime.h>

namespace {
constexpr int kH = 4, kD = 32, kEF = 32, kNT = 4, kET = 8;
constexpr int kHD = kH * kD;  // 128
constexpr float kNegSlope = 0.2f;
constexpr int kNB = 782;   // coarse buckets: dst>>7, ceil(100000/128)
constexpr int kHB = 512;   // histogram/scatter blocks

typedef _Float16 half16 __attribute__((ext_vector_type(16)));
typedef _Float16 half2v __attribute__((ext_vector_type(2)));

__device__ __forceinline__ float lrelu(float x) { return x > 0.f ? x : kNegSlope * x; }

// ee table (block 0) + per-node el/er/fs(fp16). No atomics.
__global__ void __launch_bounds__(256) k_init(
    const float* __restrict__ feat, const float* __restrict__ fc,
    const float* __restrict__ edge_emb, const float* __restrict__ W_e,
    const float* __restrict__ attn_l, const float* __restrict__ attn_r,
    const float* __restrict__ attn_e, const int* __restrict__ node_types,
    float* __restrict__ el, float* __restrict__ er, _Float16* __restrict__ fs,
    float* __restrict__ ee_tab, int N) {
  if (blockIdx.x == 0 && threadIdx.x < kET * kH) {
    int et = threadIdx.x / kH, h = threadIdx.x % kH;
    float acc = 0.f;
    for (int f = 0; f < kEF; ++f) {
      const float* wrow = W_e + (h * kEF + f) * kEF;
      const float* erow = edge_emb + et * kEF;
      float emb = 0.f;
      for (int k = 0; k < kEF; ++k) emb += erow[k] * wrow[k];
      acc += emb * attn_e[h * kEF + f];
    }
    ee_tab[et * kH + h] = acc;
  }
  int gid = blockIdx.x * blockDim.x + threadIdx.x;
  int node = gid >> 6;
  int lane = threadIdx.x & 63;
  if (node >= N) return;
  int nt = node_types[node];
  float2 f2 = *(const float2*)(feat + node * kHD + lane * 2);
  float2 c2 = *(const float2*)(fc + nt * kHD + lane * 2);
  float2 al = *(const float2*)(attn_l + lane * 2);
  float2 ar = *(const float2*)(attn_r + lane * 2);
  float fx = f2.x * c2.x, fy = f2.y * c2.y;
  half2v hv;
  hv.x = (_Float16)fx;
  hv.y = (_Float16)fy;
  *(half2v*)(fs + node * kHD + lane * 2) = hv;
  float pl = fx * al.x + fy * al.y;
  float pr = fx * ar.x + fy * ar.y;
#pragma unroll
  for (int off = 1; off < 16; off <<= 1) {
    pl += __shfl_xor(pl, off);
    pr += __shfl_xor(pr, off);
  }
  if ((lane & 15) == 0) {
    int h = lane >> 4;
    el[node * kH + h] = pl;
    er[node * kH + h] = pr;
  }
}

// per-block privatized coarse histogram (LDS atomics only)
__global__ void __launch_bounds__(256) k_hist(const int* __restrict__ dst,
                                              int* __restrict__ partial, int E) {
  __shared__ int h[kNB];
  for (int i = threadIdx.x; i < kNB; i += 256) h[i] = 0;
  __syncthreads();
  int per = (E + gridDim.x - 1) / gridDim.x;
  int e0 = blockIdx.x * per;
  int e1 = min(e0 + per, E);
  for (int i = e0 + threadIdx.x; i < e1; i += 256) atomicAdd(&h[dst[i] >> 7], 1);
  __syncthreads();
  for (int i = threadIdx.x; i < kNB; i += 256) partial[blockIdx.x * kNB + i] = h[i];
}

// column scan: one block per bucket; partial[blk][b] -> exclusive over blk; btot[b]=sum
__global__ void __launch_bounds__(256) k_scanA(int* __restrict__ partial,
                                               int* __restrict__ btot) {
  __shared__ int bufa[kHB], bufb[kHB];
  int b = blockIdx.x, t = threadIdx.x;
  bufa[t] = partial[t * kNB + b];
  bufa[t + 256] = partial[(t + 256) * kNB + b];
  __syncthreads();
  int* cur = bufa;
  int* nxt = bufb;
  for (int off = 1; off < kHB; off <<= 1) {
    for (int i = t; i < kHB; i += 256) nxt[i] = cur[i] + (i >= off ? cur[i - off] : 0);
    __syncthreads();
    int* sw = cur; cur = nxt; nxt = sw;
  }
  partial[t * kNB + b] = t ? cur[t - 1] : 0;
  partial[(t + 256) * kNB + b] = cur[t + 255];
  if (t == 0) btot[b] = cur[kHB - 1];
}

// bucket base scan (single block)
__global__ void __launch_bounds__(1024) k_scanB(const int* __restrict__ btot,
                                                int* __restrict__ bbase) {
  __shared__ int bufa[1024], bufb[1024];
  int t = threadIdx.x;
  bufa[t] = (t < kNB) ? btot[t] : 0;
  __syncthreads();
  int* cur = bufa;
  int* nxt = bufb;
  for (int off = 1; off < 1024; off <<= 1) {
    nxt[t] = cur[t] + (t >= off ? cur[t - off] : 0);
    __syncthreads();
    int* sw = cur; cur = nxt; nxt = sw;
  }
  if (t < kNB) bbase[t] = t ? cur[t - 1] : 0;
  if (t == kNB - 1) bbase[kNB] = cur[t];
}

// scatter into coarse buckets; deterministic positions, LDS-atomic local ranks
__global__ void __launch_bounds__(256) k_scatter2(
    const int* __restrict__ dst, const int* __restrict__ src,
    const int* __restrict__ e_feat, const int* __restrict__ partial,
    const int* __restrict__ bbase, int* __restrict__ tmp, int E) {
  __shared__ int h[kNB];
  for (int i = threadIdx.x; i < kNB; i += 256) h[i] = 0;
  __syncthreads();
  int per = (E + gridDim.x - 1) / gridDim.x;
  int e0 = blockIdx.x * per;
  int e1 = min(e0 + per, E);
  const int* myrow = partial + blockIdx.x * kNB;
  for (int i = e0 + threadIdx.x; i < e1; i += 256) {
    int d = dst[i];
    int b = d >> 7;
    int lr = atomicAdd(&h[b], 1);
    int pos = bbase[b] + myrow[b] + lr;
    tmp[pos] = src[i] | (e_feat[i] << 17) | ((d & 127) << 20);
  }
}

// per-bucket fine sort: write ptr + dst-sorted csr (bucket-local writes)
__global__ void __launch_bounds__(256) k_build(const int* __restrict__ bbase,
                                               const int* __restrict__ tmp,
                                               int* __restrict__ ptr,
                                               int* __restrict__ csr, int N, int E) {
  __shared__ int fh[128], fb[128], sc[128];
  int b = blockIdx.x, t = threadIdx.x;
  int s0 = bbase[b], s1 = bbase[b + 1];
  if (t < 128) fh[t] = 0;
  __syncthreads();
  for (int j = s0 + t; j < s1; j += 256) atomicAdd(&fh[tmp[j] >> 20], 1);
  __syncthreads();
  if (t < 128) sc[t] = fh[t];
  __syncthreads();
  for (int off = 1; off < 128; off <<= 1) {
    int v = 0;
    if (t < 128 && t >= off) v = sc[t - off];
    __syncthreads();
    if (t < 128) sc[t] += v;
    __syncthreads();
  }
  if (t < 128) {
    fb[t] = sc[t] - fh[t];  // exclusive
    int d = (b << 7) + t;
    if (d < N) ptr[d] = s0 + fb[t];
    fh[t] = 0;
  }
  if (b == gridDim.x - 1 && t == 0) ptr[N] = E;
  __syncthreads();
  for (int j = s0 + t; j < s1; j += 256) {
    int v = tmp[j];
    int dl = v >> 20;
    int r = atomicAdd(&fh[dl], 1);
    csr[s0 + fb[dl] + r] = v & 0xFFFFF;  // src | et<<17
  }
}

// one wave per dst node, 8 edges x 8 lanes (16 dims / lane).
__global__ void __launch_bounds__(256) k_fused(
    const _Float16* __restrict__ fs, const float* __restrict__ feat,
    const float* __restrict__ el, const float* __restrict__ er,
    const float* __restrict__ ee_tab, const int* __restrict__ ptr,
    const int* __restrict__ csr, float* __restrict__ rst,
    float* __restrict__ rinv_buf, int N) {
  __shared__ __align__(16) float ee_sh[kET * kH];
  if (threadIdx.x < kET * kH) ee_sh[threadIdx.x] = ee_tab[threadIdx.x];
  __syncthreads();
  int lane = threadIdx.x & 63;
  int node = blockIdx.x * (blockDim.x >> 6) + (threadIdx.x >> 6);
  if (node >= N) return;
  int start = ptr[node], end = ptr[node + 1];

  int g = lane >> 3;   // edge slot (8 edges in flight)
  int q = lane & 7;    // dim-lane: dims [q*16, q*16+16)
  int head = q >> 1;
  float er_h = er[node * kH + head];

  float sm = 0.f;
  half16 acch;
#pragma unroll
  for (int k = 0; k < 16; ++k) acch[k] = (_Float16)0.f;

  for (int j = start + g; j < end; j += 8) {
    int pk = csr[j];
    int s = pk & 0x1FFFF;
    int et = (pk >> 17) & 7;
    float e_h = lrelu(el[s * kH + head] + er_h + ee_sh[et * kH + head]);
    float ex = __expf(e_h);
    sm += ex;
    half16 hv = *(const half16*)(fs + s * kHD + q * 16);
    acch += hv * (_Float16)ex;  // v_pk_fma_f16 x8
  }
  float acc[16];
#pragma unroll
  for (int k = 0; k < 16; ++k) acc[k] = (float)acch[k];
  sm += __shfl_xor(sm, 8);
  sm += __shfl_xor(sm, 16);
  sm += __shfl_xor(sm, 32);
#pragma unroll
  for (int k = 0; k < 16; ++k) {
    acc[k] += __shfl_xor(acc[k], 8);
    acc[k] += __shfl_xor(acc[k], 16);
    acc[k] += __shfl_xor(acc[k], 32);
  }
  float rinv = sm > 0.f ? 1.f / sm : 0.f;

  if (g == 0) {
    const float* fr = feat + node * kHD + q * 16;
    float* out = rst + node * kHD + q * 16;
#pragma unroll
    for (int r = 0; r < 4; ++r) {
      float4 o;
      o.x = acc[r * 4 + 0] * rinv + fr[r * 4 + 0];
      o.y = acc[r * 4 + 1] * rinv + fr[r * 4 + 1];
      o.z = acc[r * 4 + 2] * rinv + fr[r * 4 + 2];
      o.w = acc[r * 4 + 3] * rinv + fr[r * 4 + 3];
      *(float4*)(out + r * 4) = o;
    }
    if ((q & 1) == 0) rinv_buf[node * kH + head] = rinv;
  }
}

// edge-parallel a computation in ORIGINAL edge order: coalesced float4 stores
__global__ void k_post(const int* __restrict__ src, const int* __restrict__ dst,
                       const int* __restrict__ e_feat, const float* __restrict__ el,
                       const float* __restrict__ er, const float* __restrict__ ee_tab,
                       const float* __restrict__ rinv_buf, float* __restrict__ out_a,
                       int E) {
  int i = blockIdx.x * blockDim.x + threadIdx.x;
  if (i >= E) return;
  int s = src[i], d = dst[i], et = e_feat[i];
  float4 elv = *(const float4*)(el + s * kH);
  float4 erv = *(const float4*)(er + d * kH);
  float4 ee = *(const float4*)(ee_tab + et * kH);
  float4 rv = *(const float4*)(rinv_buf + d * kH);
  float4 a;
  a.x = __expf(lrelu(elv.x + erv.x + ee.x)) * rv.x;
  a.y = __expf(lrelu(elv.y + erv.y + ee.y)) * rv.y;
  a.z = __expf(lrelu(elv.z + erv.z + ee.z)) * rv.z;
  a.w = __expf(lrelu(elv.w + erv.w + ee.w)) * rv.w;
  *(float4*)(out_a + (size_t)i * kH) = a;
}

}  // namespace

extern "C" void kernel_launch(void* const* d_in, const int* in_sizes, int n_in,
                              void* d_out, int out_size, void* d_ws, size_t ws_size,
                              hipStream_t stream) {
  const float* feat = (const float*)d_in[0];
  const float* fc = (const float*)d_in[1];
  const float* edge_emb = (const float*)d_in[2];
  const float* W_e = (const float*)d_in[3];
  const float* attn_l = (const float*)d_in[4];
  const float* attn_r = (const float*)d_in[5];
  const float* attn_e = (const float*)d_in[6];
  const int* node_types = (const int*)d_in[7];
  const int* e_feat = (const int*)d_in[8];
  const int* src = (const int*)d_in[9];
  const int* dst = (const int*)d_in[10];
  int N = in_sizes[7];
  int E = in_sizes[8];

  char* ws = (char*)d_ws;
  size_t off = 0;
  auto alloc = [&](size_t bytes) -> void* {
    void* p = ws + off;
    off = (off + bytes + 255) & ~(size_t)255;
    return p;
  };
  float* ee_tab = (float*)alloc((size_t)kET * kH * sizeof(float));
  float* el = (float*)alloc((size_t)N * kH * sizeof(float));
  float* er = (float*)alloc((size_t)N * kH * sizeof(float));
  float* rinv_buf = (float*)alloc((size_t)N * kH * sizeof(float));
  _Float16* fs = (_Float16*)alloc((size_t)N * kHD * sizeof(_Float16));
  int* partial = (int*)alloc((size_t)kHB * kNB * sizeof(int));
  int* btot = (int*)alloc((size_t)kNB * sizeof(int));
  int* bbase = (int*)alloc((size_t)(kNB + 1) * sizeof(int));
  int* ptr = (int*)alloc((size_t)(N + 1) * sizeof(int));
  int* tmp = (int*)alloc((size_t)E * sizeof(int));
  int* csr = (int*)alloc((size_t)E * sizeof(int));

  k_init<<<(N + 3) / 4, 256, 0, stream>>>(feat, fc, edge_emb, W_e, attn_l, attn_r,
                                          attn_e, node_types, el, er, fs, ee_tab, N);
  k_hist<<<kHB, 256, 0, stream>>>(dst, partial, E);
  k_scanA<<<kNB, 256, 0, stream>>>(partial, btot);
  k_scanB<<<1, 1024, 0, stream>>>(btot, bbase);
  k_scatter2<<<kHB, 256, 0, stream>>>(dst, src, e_feat, partial, bbase, tmp, E);
  k_build<<<kNB, 256, 0, stream>>>(bbase, tmp, ptr, csr, N, E);

  float* rst = (float*)d_out;
  float* out_a = (float*)d_out + (size_t)N * kHD;
  k_fused<<<(N + 3) / 4, 256, 0, stream>>>(fs, feat, el, er, ee_tab, ptr, csr, rst,
                                           rinv_buf, N);
  k_post<<<(E + 255) / 256, 256, 0, stream>>>(src, dst, e_feat, el, er, ee_tab,
                                              rinv_buf, out_a, E);
}

// Round 6
// 321.003 us; speedup vs baseline: 2.3878x; 1.0464x over previous
//
#include <hip/hip_runtime.h>
#include <stdint.h>

namespace {
constexpr int kH = 4, kD = 32, kEF = 32, kNT = 4, kET = 8;
constexpr int kHD = kH * kD;  // 128
constexpr float kNegSlope = 0.2f;
constexpr int kNB = 782;   // coarse buckets: dst>>7, ceil(100000/128)
constexpr int kHB = 512;   // histogram/scatter blocks

using f32x2 = __attribute__((ext_vector_type(2))) float;

__device__ __forceinline__ float lrelu(float x) { return x > 0.f ? x : kNegSlope * x; }

// ee table (block 0) + per-node el/er/fs(fp8 e4m3). No atomics.
__global__ void __launch_bounds__(256) k_init(
    const float* __restrict__ feat, const float* __restrict__ fc,
    const float* __restrict__ edge_emb, const float* __restrict__ W_e,
    const float* __restrict__ attn_l, const float* __restrict__ attn_r,
    const float* __restrict__ attn_e, const int* __restrict__ node_types,
    float* __restrict__ el, float* __restrict__ er, uint8_t* __restrict__ fs,
    float* __restrict__ ee_tab, int N) {
  if (blockIdx.x == 0 && threadIdx.x < kET * kH) {
    int et = threadIdx.x / kH, h = threadIdx.x % kH;
    float acc = 0.f;
    for (int f = 0; f < kEF; ++f) {
      const float* wrow = W_e + (h * kEF + f) * kEF;
      const float* erow = edge_emb + et * kEF;
      float emb = 0.f;
      for (int k = 0; k < kEF; ++k) emb += erow[k] * wrow[k];
      acc += emb * attn_e[h * kEF + f];
    }
    ee_tab[et * kH + h] = acc;
  }
  int gid = blockIdx.x * blockDim.x + threadIdx.x;
  int node = gid >> 6;
  int lane = threadIdx.x & 63;
  if (node >= N) return;
  int nt = node_types[node];
  float2 f2 = *(const float2*)(feat + node * kHD + lane * 2);
  float2 c2 = *(const float2*)(fc + nt * kHD + lane * 2);
  float2 al = *(const float2*)(attn_l + lane * 2);
  float2 ar = *(const float2*)(attn_r + lane * 2);
  float fx = f2.x * c2.x, fy = f2.y * c2.y;
  // pack 4 dims (this lane's 2 + odd neighbor's 2) into one fp8x4 word on even lanes
  float nx = __shfl_down(fx, 1);
  float ny = __shfl_down(fy, 1);
  if ((lane & 1) == 0) {
    int w = __builtin_amdgcn_cvt_pk_fp8_f32(fx, fy, 0, false);
    w = __builtin_amdgcn_cvt_pk_fp8_f32(nx, ny, w, true);
    *(int*)(fs + (size_t)node * kHD + lane * 2) = w;
  }
  float pl = fx * al.x + fy * al.y;
  float pr = fx * ar.x + fy * ar.y;
#pragma unroll
  for (int off = 1; off < 16; off <<= 1) {
    pl += __shfl_xor(pl, off);
    pr += __shfl_xor(pr, off);
  }
  if ((lane & 15) == 0) {
    int h = lane >> 4;
    el[node * kH + h] = pl;
    er[node * kH + h] = pr;
  }
}

// per-block privatized coarse histogram (LDS atomics only)
__global__ void __launch_bounds__(256) k_hist(const int* __restrict__ dst,
                                              int* __restrict__ partial, int E) {
  __shared__ int h[kNB];
  for (int i = threadIdx.x; i < kNB; i += 256) h[i] = 0;
  __syncthreads();
  int per = (E + gridDim.x - 1) / gridDim.x;
  int e0 = blockIdx.x * per;
  int e1 = min(e0 + per, E);
  for (int i = e0 + threadIdx.x; i < e1; i += 256) atomicAdd(&h[dst[i] >> 7], 1);
  __syncthreads();
  for (int i = threadIdx.x; i < kNB; i += 256) partial[blockIdx.x * kNB + i] = h[i];
}

// column scan: one block per bucket; partial[blk][b] -> exclusive over blk; btot[b]=sum
__global__ void __launch_bounds__(256) k_scanA(int* __restrict__ partial,
                                               int* __restrict__ btot) {
  __shared__ int bufa[kHB], bufb[kHB];
  int b = blockIdx.x, t = threadIdx.x;
  bufa[t] = partial[t * kNB + b];
  bufa[t + 256] = partial[(t + 256) * kNB + b];
  __syncthreads();
  int* cur = bufa;
  int* nxt = bufb;
  for (int off = 1; off < kHB; off <<= 1) {
    for (int i = t; i < kHB; i += 256) nxt[i] = cur[i] + (i >= off ? cur[i - off] : 0);
    __syncthreads();
    int* sw = cur; cur = nxt; nxt = sw;
  }
  partial[t * kNB + b] = t ? cur[t - 1] : 0;
  partial[(t + 256) * kNB + b] = cur[t + 255];
  if (t == 0) btot[b] = cur[kHB - 1];
}

// bucket base scan (single block)
__global__ void __launch_bounds__(1024) k_scanB(const int* __restrict__ btot,
                                                int* __restrict__ bbase) {
  __shared__ int bufa[1024], bufb[1024];
  int t = threadIdx.x;
  bufa[t] = (t < kNB) ? btot[t] : 0;
  __syncthreads();
  int* cur = bufa;
  int* nxt = bufb;
  for (int off = 1; off < 1024; off <<= 1) {
    nxt[t] = cur[t] + (t >= off ? cur[t - off] : 0);
    __syncthreads();
    int* sw = cur; cur = nxt; nxt = sw;
  }
  if (t < kNB) bbase[t] = t ? cur[t - 1] : 0;
  if (t == kNB - 1) bbase[kNB] = cur[t];
}

// scatter into coarse buckets; deterministic positions, LDS-atomic local ranks
__global__ void __launch_bounds__(256) k_scatter2(
    const int* __restrict__ dst, const int* __restrict__ src,
    const int* __restrict__ e_feat, const int* __restrict__ partial,
    const int* __restrict__ bbase, int* __restrict__ tmp, int E) {
  __shared__ int h[kNB];
  for (int i = threadIdx.x; i < kNB; i += 256) h[i] = 0;
  __syncthreads();
  int per = (E + gridDim.x - 1) / gridDim.x;
  int e0 = blockIdx.x * per;
  int e1 = min(e0 + per, E);
  const int* myrow = partial + blockIdx.x * kNB;
  for (int i = e0 + threadIdx.x; i < e1; i += 256) {
    int d = dst[i];
    int b = d >> 7;
    int lr = atomicAdd(&h[b], 1);
    int pos = bbase[b] + myrow[b] + lr;
    tmp[pos] = src[i] | (e_feat[i] << 17) | ((d & 127) << 20);
  }
}

// per-bucket fine sort: write ptr + dst-sorted csr (bucket-local writes)
__global__ void __launch_bounds__(256) k_build(const int* __restrict__ bbase,
                                               const int* __restrict__ tmp,
                                               int* __restrict__ ptr,
                                               int* __restrict__ csr, int N, int E) {
  __shared__ int fh[128], fb[128], sc[128];
  int b = blockIdx.x, t = threadIdx.x;
  int s0 = bbase[b], s1 = bbase[b + 1];
  if (t < 128) fh[t] = 0;
  __syncthreads();
  for (int j = s0 + t; j < s1; j += 256) atomicAdd(&fh[tmp[j] >> 20], 1);
  __syncthreads();
  if (t < 128) sc[t] = fh[t];
  __syncthreads();
  for (int off = 1; off < 128; off <<= 1) {
    int v = 0;
    if (t < 128 && t >= off) v = sc[t - off];
    __syncthreads();
    if (t < 128) sc[t] += v;
    __syncthreads();
  }
  if (t < 128) {
    fb[t] = sc[t] - fh[t];  // exclusive
    int d = (b << 7) + t;
    if (d < N) ptr[d] = s0 + fb[t];
    fh[t] = 0;
  }
  if (b == gridDim.x - 1 && t == 0) ptr[N] = E;
  __syncthreads();
  for (int j = s0 + t; j < s1; j += 256) {
    int v = tmp[j];
    int dl = v >> 20;
    int r = atomicAdd(&fh[dl], 1);
    csr[s0 + fb[dl] + r] = v & 0xFFFFF;  // src | et<<17
  }
}

// one wave per dst node, 8 edges x 8 lanes (16 dims / lane, fp8 rows).
__global__ void __launch_bounds__(256) k_fused(
    const uint8_t* __restrict__ fs, const float* __restrict__ feat,
    const float* __restrict__ el, const float* __restrict__ er,
    const float* __restrict__ ee_tab, const int* __restrict__ ptr,
    const int* __restrict__ csr, float* __restrict__ rst,
    float* __restrict__ rinv_buf, int N) {
  __shared__ __align__(16) float ee_sh[kET * kH];
  if (threadIdx.x < kET * kH) ee_sh[threadIdx.x] = ee_tab[threadIdx.x];
  __syncthreads();
  int lane = threadIdx.x & 63;
  int node = blockIdx.x * (blockDim.x >> 6) + (threadIdx.x >> 6);
  if (node >= N) return;
  int start = ptr[node], end = ptr[node + 1];

  int g = lane >> 3;   // edge slot (8 edges in flight)
  int q = lane & 7;    // dim-lane: dims [q*16, q*16+16)
  int head = q >> 1;
  float er_h = er[node * kH + head];

  float sm = 0.f;
  float acc[16];
#pragma unroll
  for (int k = 0; k < 16; ++k) acc[k] = 0.f;

  for (int j = start + g; j < end; j += 8) {
    int pk = csr[j];
    int s = pk & 0x1FFFF;
    int et = (pk >> 17) & 7;
    float e_h = lrelu(el[s * kH + head] + er_h + ee_sh[et * kH + head]);
    float ex = __expf(e_h);
    sm += ex;
    int4 w = *(const int4*)(fs + (size_t)s * kHD + q * 16);
#pragma unroll
    for (int c = 0; c < 4; ++c) {
      int wc = c == 0 ? w.x : c == 1 ? w.y : c == 2 ? w.z : w.w;
      f32x2 lo = __builtin_amdgcn_cvt_pk_f32_fp8(wc, false);
      f32x2 hi = __builtin_amdgcn_cvt_pk_f32_fp8(wc, true);
      acc[c * 4 + 0] += ex * lo.x;
      acc[c * 4 + 1] += ex * lo.y;
      acc[c * 4 + 2] += ex * hi.x;
      acc[c * 4 + 3] += ex * hi.y;
    }
  }
  sm += __shfl_xor(sm, 8);
  sm += __shfl_xor(sm, 16);
  sm += __shfl_xor(sm, 32);
#pragma unroll
  for (int k = 0; k < 16; ++k) {
    acc[k] += __shfl_xor(acc[k], 8);
    acc[k] += __shfl_xor(acc[k], 16);
    acc[k] += __shfl_xor(acc[k], 32);
  }
  float rinv = sm > 0.f ? 1.f / sm : 0.f;

  if (g == 0) {
    const float* fr = feat + node * kHD + q * 16;
    float* out = rst + node * kHD + q * 16;
#pragma unroll
    for (int r = 0; r < 4; ++r) {
      float4 o;
      o.x = acc[r * 4 + 0] * rinv + fr[r * 4 + 0];
      o.y = acc[r * 4 + 1] * rinv + fr[r * 4 + 1];
      o.z = acc[r * 4 + 2] * rinv + fr[r * 4 + 2];
      o.w = acc[r * 4 + 3] * rinv + fr[r * 4 + 3];
      *(float4*)(out + r * 4) = o;
    }
    if ((q & 1) == 0) rinv_buf[node * kH + head] = rinv;
  }
}

// edge-parallel a computation in ORIGINAL edge order: coalesced float4 stores
__global__ void k_post(const int* __restrict__ src, const int* __restrict__ dst,
                       const int* __restrict__ e_feat, const float* __restrict__ el,
                       const float* __restrict__ er, const float* __restrict__ ee_tab,
                       const float* __restrict__ rinv_buf, float* __restrict__ out_a,
                       int E) {
  int i = blockIdx.x * blockDim.x + threadIdx.x;
  if (i >= E) return;
  int s = src[i], d = dst[i], et = e_feat[i];
  float4 elv = *(const float4*)(el + s * kH);
  float4 erv = *(const float4*)(er + d * kH);
  float4 ee = *(const float4*)(ee_tab + et * kH);
  float4 rv = *(const float4*)(rinv_buf + d * kH);
  float4 a;
  a.x = __expf(lrelu(elv.x + erv.x + ee.x)) * rv.x;
  a.y = __expf(lrelu(elv.y + erv.y + ee.y)) * rv.y;
  a.z = __expf(lrelu(elv.z + erv.z + ee.z)) * rv.z;
  a.w = __expf(lrelu(elv.w + erv.w + ee.w)) * rv.w;
  *(float4*)(out_a + (size_t)i * kH) = a;
}

}  // namespace

extern "C" void kernel_launch(void* const* d_in, const int* in_sizes, int n_in,
                              void* d_out, int out_size, void* d_ws, size_t ws_size,
                              hipStream_t stream) {
  const float* feat = (const float*)d_in[0];
  const float* fc = (const float*)d_in[1];
  const float* edge_emb = (const float*)d_in[2];
  const float* W_e = (const float*)d_in[3];
  const float* attn_l = (const float*)d_in[4];
  const float* attn_r = (const float*)d_in[5];
  const float* attn_e = (const float*)d_in[6];
  const int* node_types = (const int*)d_in[7];
  const int* e_feat = (const int*)d_in[8];
  const int* src = (const int*)d_in[9];
  const int* dst = (const int*)d_in[10];
  int N = in_sizes[7];
  int E = in_sizes[8];

  char* ws = (char*)d_ws;
  size_t off = 0;
  auto alloc = [&](size_t bytes) -> void* {
    void* p = ws + off;
    off = (off + bytes + 255) & ~(size_t)255;
    return p;
  };
  float* ee_tab = (float*)alloc((size_t)kET * kH * sizeof(float));
  float* el = (float*)alloc((size_t)N * kH * sizeof(float));
  float* er = (float*)alloc((size_t)N * kH * sizeof(float));
  float* rinv_buf = (float*)alloc((size_t)N * kH * sizeof(float));
  uint8_t* fs = (uint8_t*)alloc((size_t)N * kHD * sizeof(uint8_t));
  int* partial = (int*)alloc((size_t)kHB * kNB * sizeof(int));
  int* btot = (int*)alloc((size_t)kNB * sizeof(int));
  int* bbase = (int*)alloc((size_t)(kNB + 1) * sizeof(int));
  int* ptr = (int*)alloc((size_t)(N + 1) * sizeof(int));
  int* tmp = (int*)alloc((size_t)E * sizeof(int));
  int* csr = (int*)alloc((size_t)E * sizeof(int));

  k_init<<<(N + 3) / 4, 256, 0, stream>>>(feat, fc, edge_emb, W_e, attn_l, attn_r,
                                          attn_e, node_types, el, er, fs, ee_tab, N);
  k_hist<<<kHB, 256, 0, stream>>>(dst, partial, E);
  k_scanA<<<kNB, 256, 0, stream>>>(partial, btot);
  k_scanB<<<1, 1024, 0, stream>>>(btot, bbase);
  k_scatter2<<<kHB, 256, 0, stream>>>(dst, src, e_feat, partial, bbase, tmp, E);
  k_build<<<kNB, 256, 0, stream>>>(bbase, tmp, ptr, csr, N, E);

  float* rst = (float*)d_out;
  float* out_a = (float*)d_out + (size_t)N * kHD;
  k_fused<<<(N + 3) / 4, 256, 0, stream>>>(fs, feat, el, er, ee_tab, ptr, csr, rst,
                                           rinv_buf, N);
  k_post<<<(E + 255) / 256, 256, 0, stream>>>(src, dst, e_feat, el, er, ee_tab,
                                              rinv_buf, out_a, E);
}